// Round 7
// baseline (255.692 us; speedup 1.0000x reference)
//
#include <hip/hip_runtime.h>
#include <hip/hip_bf16.h>
#include <math.h>

// MultiHash: Instant-NGP 2D multires hash encoding (L=16, T=2^14, F=2)
// + MLP 32 -> 64 -> 64 -> 3 over B=1M samples. Split-bf16 MFMA MLP
// (x = hi+lo bf16; A*B ~= Al*Bh + Ah*Bl + Ah*Bh) — validated in R6
// (absmax 1.49e-8, identical to full-fp32 path).
//
// R7 changes (R6 was latency-bound: Occupancy 21%, MfmaUtil 9.5%):
//  1. LDS 19456 -> 10240 B: hoist all layer-1 A-fragments (both 32-sample
//     halves, 8 frags = 32 VGPRs) into registers right after encoding, then
//     ALIAS the h1/h2 staging region over the dead feat region (same-wave DS
//     ops are in-order; 1 wave/block so no cross-wave hazard). 15 blocks/CU
//     by LDS; VGPR (~120) binds at 4 waves/SIMD -> ~50% occupancy ceiling
//     vs R6's 25%.
//  2. Weight split hoisted out of the hot loop: prep kernel converts
//     W1/W2/W3 (W3 zero-padded to 16 rows -> no lane<3 branch) to hi/lo bf16
//     in d_ws once per launch; main kernel loads B-frags as single 16B
//     global loads (L1-resident). Removes ~670 VALU + 56 fp32 loads/wave.

#define TBL_MASK 16383u
#define PRIME1   2654435761u

typedef __attribute__((ext_vector_type(8))) short short8;
typedef __attribute__((ext_vector_type(4))) float f32x4;
typedef __attribute__((ext_vector_type(4))) unsigned int uint4v;

struct ResArr { float r[16]; };

// ws layout (ushort offsets):
//  W1h @ 0      (64*32 = 2048)   W1l @ 2048
//  W2h @ 4096   (64*64 = 4096)   W2l @ 8192
//  W3h @ 12288  (16*64 = 1024, rows 3..15 zero)   W3l @ 13312
// total 14336 ushort = 28672 B  (ws_size is MBs; fits)
#define WS_W1H 0
#define WS_W1L 2048
#define WS_W2H 4096
#define WS_W2L 8192
#define WS_W3H 12288
#define WS_W3L 13312

__device__ __forceinline__ unsigned short bf16rn(float f) {
    __hip_bfloat16 h = __float2bfloat16(f);   // RNE
    return __builtin_bit_cast(unsigned short, h);
}
__device__ __forceinline__ float bf16tof(unsigned short u) {
    unsigned int x = ((unsigned int)u) << 16;
    return __builtin_bit_cast(float, x);
}
__device__ __forceinline__ short8 ldFrag(const unsigned short* p) {
    return __builtin_bit_cast(short8, *(const uint4v*)p);
}

#define MFMA(a, b, c) __builtin_amdgcn_mfma_f32_16x16x32_bf16((a), (b), (c), 0, 0, 0)

__global__ __launch_bounds__(256) void prep_weights(
    const float* __restrict__ W1,
    const float* __restrict__ W2,
    const float* __restrict__ W3,
    unsigned short* __restrict__ ws)
{
    const int t = blockIdx.x * 256 + threadIdx.x;
    if (t < 2048) {                       // W1: 64x32
        const float v = W1[t];
        const unsigned short hb = bf16rn(v);
        ws[WS_W1H + t] = hb;
        ws[WS_W1L + t] = bf16rn(v - bf16tof(hb));
    } else if (t < 2048 + 4096) {         // W2: 64x64
        const int i = t - 2048;
        const float v = W2[i];
        const unsigned short hb = bf16rn(v);
        ws[WS_W2H + i] = hb;
        ws[WS_W2L + i] = bf16rn(v - bf16tof(hb));
    } else if (t < 2048 + 4096 + 1024) {  // W3: 3x64 padded to 16x64
        const int i = t - 6144;
        const int r = i >> 6, c = i & 63;
        const float v = (r < 3) ? W3[r * 64 + c] : 0.0f;
        const unsigned short hb = bf16rn(v);
        ws[WS_W3H + i] = hb;
        ws[WS_W3L + i] = bf16rn(v - bf16tof(hb));
    }
}

__global__ __launch_bounds__(64) void mh_mfma(
    const float* __restrict__ x,
    const float* __restrict__ tables,
    const float* __restrict__ b1,
    const float* __restrict__ b2,
    const float* __restrict__ b3,
    const unsigned short* __restrict__ ws,
    float* __restrict__ out,
    ResArr res, int n)
{
    // Single 10240 B region, two overlapping uses (feat dies before sA born):
    //  feat: rows [64 samples] stride 40 ushort; hi @ 0, lo @ 2560 ushort
    //  sA  : rows [32] stride 72 ushort; hi @ 0, lo @ 2304 ushort (4608 B)
    __shared__ char smem[10240];
    unsigned short* sF  = (unsigned short*)smem;
    unsigned short* sAH = (unsigned short*)smem;
    unsigned short* sAL = (unsigned short*)(smem + 4608);

    const int L  = threadIdx.x;
    const int ln = L & 15;
    const int q  = L >> 4;
    const long base = (long)blockIdx.x * 64;
    long s = base + L;
    if (s >= (long)n) s = (long)n - 1;   // clamp loads; stores predicated below

    const float2 xv = reinterpret_cast<const float2*>(x)[s];
    const float2* __restrict__ tbl2 = reinterpret_cast<const float2*>(tables);

    // ---- encoding (R1-exact math): feat -> LDS as hi/lo bf16 ---------------
    #pragma unroll 8
    for (int l = 0; l < 16; ++l) {
        const float r  = res.r[l];
        const float sx = xv.x * r;
        const float sy = xv.y * r;
        const float gx = floorf(sx);
        const float gy = floorf(sy);
        const unsigned ux = (unsigned)(int)gx;
        const unsigned uy = (unsigned)(int)gy;
        const unsigned hy0 = uy * PRIME1;
        const unsigned hy1 = hy0 + PRIME1;
        const unsigned i00 = ( ux       ^ hy0) & TBL_MASK;
        const unsigned i10 = ((ux + 1u) ^ hy0) & TBL_MASK;
        const unsigned i01 = ( ux       ^ hy1) & TBL_MASK;
        const unsigned i11 = ((ux + 1u) ^ hy1) & TBL_MASK;
        const float2* tl = tbl2 + (l << 14);
        const float2 t00 = tl[i00];
        const float2 t10 = tl[i10];
        const float2 t01 = tl[i01];
        const float2 t11 = tl[i11];
        const float wx0 = 1.0f - fabsf(sx - gx);
        const float wx1 = 1.0f - fabsf(sx - (gx + 1.0f));
        const float wy0 = 1.0f - fabsf(sy - gy);
        const float wy1 = 1.0f - fabsf(sy - (gy + 1.0f));
        const float w00 = wx0 * wy0;
        const float w10 = wx1 * wy0;
        const float w01 = wx0 * wy1;
        const float w11 = wx1 * wy1;
        const float f0 = fmaf(w00, t00.x, fmaf(w10, t10.x, fmaf(w01, t01.x, w11 * t11.x)));
        const float f1 = fmaf(w00, t00.y, fmaf(w10, t10.y, fmaf(w01, t01.y, w11 * t11.y)));
        const unsigned short h0 = bf16rn(f0);
        const unsigned short h1e = bf16rn(f1);
        const unsigned short l0 = bf16rn(f0 - bf16tof(h0));
        const unsigned short l1 = bf16rn(f1 - bf16tof(h1e));
        *(unsigned int*)&sF[L * 40 + 2 * l]        = (unsigned)h0 | ((unsigned)h1e << 16);
        *(unsigned int*)&sF[2560 + L * 40 + 2 * l] = (unsigned)l0 | ((unsigned)l1 << 16);
    }

    // ---- hoist ALL layer-1 A-frags (both halves) before feat region dies ---
    short8 fah[2][2], fal[2][2];        // [mh][mt]
    #pragma unroll
    for (int mh = 0; mh < 2; ++mh)
        #pragma unroll
        for (int mt = 0; mt < 2; ++mt) {
            const int row = mh * 32 + mt * 16 + ln;
            fah[mh][mt] = ldFrag(&sF[row * 40 + q * 8]);
            fal[mh][mt] = ldFrag(&sF[2560 + row * 40 + q * 8]);
        }

    // biases (per-lane by output column)
    float b1v[4], b2v[4];
    #pragma unroll
    for (int nt = 0; nt < 4; ++nt) { b1v[nt] = b1[nt * 16 + ln]; b2v[nt] = b2[nt * 16 + ln]; }
    const float b3v = (ln < 3) ? b3[ln] : 0.0f;

    const f32x4 zero4 = {0.0f, 0.0f, 0.0f, 0.0f};

    for (int mh = 0; mh < 2; ++mh) {          // 32-sample halves
        // ---------------- layer 1 ----------------
        f32x4 acc1[2][4];
        #pragma unroll
        for (int mt = 0; mt < 2; ++mt)
            #pragma unroll
            for (int nt = 0; nt < 4; ++nt) acc1[mt][nt] = zero4;

        #pragma unroll
        for (int nt = 0; nt < 4; ++nt) {
            const int off = (nt * 16 + ln) * 32 + q * 8;
            const short8 bh = ldFrag(ws + WS_W1H + off);
            const short8 bl = ldFrag(ws + WS_W1L + off);
            #pragma unroll
            for (int mt = 0; mt < 2; ++mt) {
                f32x4 a = acc1[mt][nt];
                a = MFMA(fal[mh][mt], bh, a);
                a = MFMA(fah[mh][mt], bl, a);
                a = MFMA(fah[mh][mt], bh, a);
                acc1[mt][nt] = a;
            }
        }
        // epilogue: bias + relu + split -> sAH/sAL rows 0..31
        #pragma unroll
        for (int mt = 0; mt < 2; ++mt)
            #pragma unroll
            for (int nt = 0; nt < 4; ++nt) {
                const int col = nt * 16 + ln;
                #pragma unroll
                for (int r = 0; r < 4; ++r) {
                    float v = fmaxf(acc1[mt][nt][r] + b1v[nt], 0.0f);
                    const unsigned short hb = bf16rn(v);
                    const unsigned short lb = bf16rn(v - bf16tof(hb));
                    const int rl = mt * 16 + q * 4 + r;
                    sAH[rl * 72 + col] = hb;
                    sAL[rl * 72 + col] = lb;
                }
            }

        // ---------------- layer 2 ----------------
        short8 a2h[2][2], a2l[2][2];
        #pragma unroll
        for (int mt = 0; mt < 2; ++mt)
            #pragma unroll
            for (int ks = 0; ks < 2; ++ks) {
                const int row = mt * 16 + ln;
                a2h[mt][ks] = ldFrag(&sAH[row * 72 + ks * 32 + q * 8]);
                a2l[mt][ks] = ldFrag(&sAL[row * 72 + ks * 32 + q * 8]);
            }
        f32x4 acc2[2][4];
        #pragma unroll
        for (int mt = 0; mt < 2; ++mt)
            #pragma unroll
            for (int nt = 0; nt < 4; ++nt) acc2[mt][nt] = zero4;

        #pragma unroll
        for (int nt = 0; nt < 4; ++nt)
            #pragma unroll
            for (int ks = 0; ks < 2; ++ks) {
                const int off = (nt * 16 + ln) * 64 + ks * 32 + q * 8;
                const short8 bh = ldFrag(ws + WS_W2H + off);
                const short8 bl = ldFrag(ws + WS_W2L + off);
                #pragma unroll
                for (int mt = 0; mt < 2; ++mt) {
                    f32x4 a = acc2[mt][nt];
                    a = MFMA(a2l[mt][ks], bh, a);
                    a = MFMA(a2h[mt][ks], bl, a);
                    a = MFMA(a2h[mt][ks], bh, a);
                    acc2[mt][nt] = a;
                }
            }
        // epilogue: bias + relu + split -> overwrite sAH/sAL (same-wave
        // in-order DS; A-frags already read)
        #pragma unroll
        for (int mt = 0; mt < 2; ++mt)
            #pragma unroll
            for (int nt = 0; nt < 4; ++nt) {
                const int col = nt * 16 + ln;
                #pragma unroll
                for (int r = 0; r < 4; ++r) {
                    float v = fmaxf(acc2[mt][nt][r] + b2v[nt], 0.0f);
                    const unsigned short hb = bf16rn(v);
                    const unsigned short lb = bf16rn(v - bf16tof(hb));
                    const int rl = mt * 16 + q * 4 + r;
                    sAH[rl * 72 + col] = hb;
                    sAL[rl * 72 + col] = lb;
                }
            }

        // ---------------- layer 3 ----------------
        short8 a3h[2][2], a3l[2][2];
        #pragma unroll
        for (int mt = 0; mt < 2; ++mt)
            #pragma unroll
            for (int ks = 0; ks < 2; ++ks) {
                const int row = mt * 16 + ln;
                a3h[mt][ks] = ldFrag(&sAH[row * 72 + ks * 32 + q * 8]);
                a3l[mt][ks] = ldFrag(&sAL[row * 72 + ks * 32 + q * 8]);
            }
        f32x4 acc3[2] = {zero4, zero4};
        #pragma unroll
        for (int ks = 0; ks < 2; ++ks) {
            const int off = ln * 64 + ks * 32 + q * 8;   // W3 padded: rows>=3 zero
            const short8 bh = ldFrag(ws + WS_W3H + off);
            const short8 bl = ldFrag(ws + WS_W3L + off);
            #pragma unroll
            for (int mt = 0; mt < 2; ++mt) {
                f32x4 a = acc3[mt];
                a = MFMA(a3l[mt][ks], bh, a);
                a = MFMA(a3h[mt][ks], bl, a);
                a = MFMA(a3h[mt][ks], bh, a);
                acc3[mt] = a;
            }
        }
        // store: C col = ln (channel, <3), rows = samples
        if (ln < 3) {
            #pragma unroll
            for (int mt = 0; mt < 2; ++mt)
                #pragma unroll
                for (int r = 0; r < 4; ++r) {
                    const long sg = base + mh * 32 + mt * 16 + q * 4 + r;
                    if (sg < (long)n) out[sg * 3 + ln] = acc3[mt][r] + b3v;
                }
        }
    }
}

extern "C" void kernel_launch(void* const* d_in, const int* in_sizes, int n_in,
                              void* d_out, int out_size, void* d_ws, size_t ws_size,
                              hipStream_t stream) {
    const float* x      = (const float*)d_in[0];
    const float* tables = (const float*)d_in[1];
    const float* W1     = (const float*)d_in[2];
    const float* b1v    = (const float*)d_in[3];
    const float* W2     = (const float*)d_in[4];
    const float* b2v    = (const float*)d_in[5];
    const float* W3     = (const float*)d_in[6];
    const float* b3v    = (const float*)d_in[7];
    float* out = (float*)d_out;
    unsigned short* ws = (unsigned short*)d_ws;

    const int n = in_sizes[0] / 2;   // B

    // Replicate numpy's RES computation on the host (glibc libm, float64).
    ResArr ra;
    const double bb = exp((log(512.0) - log(16.0)) / 15.0);
    for (int k = 0; k < 16; ++k) ra.r[k] = (float)floor(16.0 * pow(bb, (double)k));

    hipLaunchKernelGGL(prep_weights, dim3(28), dim3(256), 0, stream, W1, W2, W3, ws);
    hipLaunchKernelGGL(mh_mfma, dim3((n + 63) / 64), dim3(64), 0, stream,
                       x, tables, b1v, b2v, b3v, ws, out, ra, n);
}